// Round 12
// baseline (185.603 us; speedup 1.0000x reference)
//
#include <hip/hip_runtime.h>

#define DOUT 256
#define NROWS 49152              // 64 king squares * 12 planes * 64 squares
#define MATB (NROWS / 16)        // 3072 materialize blocks of 1024 threads

typedef float fx4 __attribute__((ext_vector_type(4)));
typedef unsigned ux2 __attribute__((ext_vector_type(2)));

__device__ __forceinline__ float4 ld4(const float* p) {
  return *reinterpret_cast<const float4*>(p);
}

// round-to-nearest-even f32 -> bf16, packed pair (a in low16, b in high16)
__device__ __forceinline__ unsigned rne2(float a, float b) {
  unsigned ua = __float_as_uint(a), ub = __float_as_uint(b);
  ua += 0x7FFFu + ((ua >> 16) & 1u);
  ub += 0x7FFFu + ((ub >> 16) & 1u);
  return (ua >> 16) | (ub & 0xFFFF0000u);
}

// accumulate 4 bf16 (packed in uint2) into float4
__device__ __forceinline__ void bf4_acc(uint2 w, float4& acc) {
  acc.x += __uint_as_float(w.x << 16);
  acc.y += __uint_as_float(w.x & 0xFFFF0000u);
  acc.z += __uint_as_float(w.y << 16);
  acc.w += __uint_as_float(w.y & 0xFFFF0000u);
}

// prep: block 0 = index work -> king-sorted per-bag metadata
//   meta_m/meta_w[pos] = {ragged_off, len, rowBase(king), bag}
// blocks 1..MATB = bf16 table materialize (NT loads of tiles, NT stores).
__global__ __launch_bounds__(1024) void prep_kernel(
    const float* __restrict__ tiles, const float* __restrict__ pieces,
    const float* __restrict__ ranks, const float* __restrict__ files,
    const float* __restrict__ mask, uint2* __restrict__ merged,
    const int* __restrict__ lengths, const int* __restrict__ kings,
    int4* __restrict__ meta_m, int4* __restrict__ meta_w, int n_bags) {
  const int bid = blockIdx.x;
  const int t = threadIdx.x;
  if (bid == 0) {
    __shared__ int wsum[16];
    __shared__ int histM[16][64];
    __shared__ int histW[16][64];
    const int nb = n_bags;
    const int lane = t & 63;
    const int wid = t >> 6;
    // ---- zero hists (2048 ints / 1024 threads) ----
    ((int*)histM)[t] = 0;
    ((int*)histW)[t] = 0;
    // ---- lengths for this thread's 16 bags + local sum ----
    int v[16];
    const int base16 = t * 16;
    int s = 0;
    if (base16 + 16 <= nb) {
#pragma unroll
      for (int j = 0; j < 16; j += 4) {
        const int4 x = *reinterpret_cast<const int4*>(lengths + base16 + j);
        v[j] = x.x; v[j + 1] = x.y; v[j + 2] = x.z; v[j + 3] = x.w;
      }
#pragma unroll
      for (int j = 0; j < 16; ++j) s += v[j];
    } else {
      for (int j = 0; j < 16; ++j) {
        const int idx = base16 + j;
        v[j] = (idx < nb) ? lengths[idx] : 0;
        s += v[j];
      }
    }
    // ---- wave-level inclusive scan via shuffles ----
    int inc = s;
#pragma unroll
    for (int d = 1; d < 64; d <<= 1) {
      const int y = __shfl_up(inc, d, 64);
      if (lane >= d) inc += y;
    }
    if (lane == 63) wsum[wid] = inc;
    __syncthreads();
    if (wid == 0) {
      int wv = (lane < 16) ? wsum[lane] : 0;
#pragma unroll
      for (int d = 1; d < 16; d <<= 1) {
        const int y = __shfl_up(wv, d, 64);
        if (lane >= d) wv += y;
      }
      if (lane < 16) wsum[lane] = wv;  // inclusive wave totals
    }
    __syncthreads();
    const int waveBase = wid ? wsum[wid - 1] : 0;
    const int run0 = waveBase + inc - s;  // exclusive ragged offset of bag base16
    // ---- per-wave dual histogram ----
    for (int j = 0; j < 16; ++j) {
      const int idx = base16 + j;
      if (idx < nb) {
        const int2 kk = *reinterpret_cast<const int2*>(kings + 2 * idx);
        atomicAdd(&histM[wid][kk.x], 1);
        atomicAdd(&histW[wid][kk.y], 1);
      }
    }
    __syncthreads();
    // ---- bucket starts + per-wave cursor bases (wave0: M, wave1: W) ----
    if (wid < 2) {
      int (*h)[64] = wid ? histW : histM;
      const int k = lane;
      int sum = 0;
#pragma unroll
      for (int w = 0; w < 16; ++w) sum += h[w][k];
      int incl = sum;
#pragma unroll
      for (int d = 1; d < 64; d <<= 1) {
        const int y = __shfl_up(incl, d, 64);
        if (k >= d) incl += y;
      }
      int run = incl - sum;  // global bucket start
#pragma unroll
      for (int w = 0; w < 16; ++w) { const int c = h[w][k]; h[w][k] = run; run += c; }
    }
    __syncthreads();
    // ---- scatter packed metadata for both views ----
    int off = run0;
    for (int j = 0; j < 16; ++j) {
      const int idx = base16 + j;
      if (idx < nb) {
        const int2 kk = *reinterpret_cast<const int2*>(kings + 2 * idx);  // L1-hot
        const int len = v[j];
        const int pm = atomicAdd(&histM[wid][kk.x], 1);
        meta_m[pm] = make_int4(off, len, kk.x * 768, idx);
        const int sw = ((7 - (kk.y >> 3)) << 3) + (kk.y & 7);  // flipped king sq
        const int pw = atomicAdd(&histW[wid][kk.y], 1);
        meta_w[pw] = make_int4(off, len, sw * 768, idx);
        off += len;
      }
    }
    return;
  }
  // ---- materialize: 16 rows per block; NT tiles loads, NT merged stores ----
  const int row = ((bid - 1) << 4) + (t >> 6);
  const int lane = t & 63;
  const int p = row & 63;
  const int sk = row >> 6;
  const int r = p >> 3, f = p & 7;
  const float m = mask[row];
  const int d0 = lane << 2;
  const fx4 tlv = __builtin_nontemporal_load(
      reinterpret_cast<const fx4*>(tiles + (size_t)row * DOUT + d0));
  const float4 pc = ld4(pieces + (size_t)sk * DOUT + d0);
  const float4 rk = ld4(ranks + (size_t)(sk * 8 + r) * DOUT + d0);
  const float4 fl = ld4(files + (size_t)(sk * 8 + f) * DOUT + d0);
  float4 o;
  o.x = fmaf(pc.x + rk.x + fl.x, m, tlv.x);
  o.y = fmaf(pc.y + rk.y + fl.y, m, tlv.y);
  o.z = fmaf(pc.z + rk.z + fl.z, m, tlv.z);
  o.w = fmaf(pc.w + rk.w + fl.w, m, tlv.w);
  ux2 w;
  w.x = rne2(o.x, o.y);
  w.y = rne2(o.z, o.w);
  __builtin_nontemporal_store(
      w, reinterpret_cast<ux2*>(&merged[(size_t)row * 64 + lane]));
}

// gather: one wave per bag over the bf16 table; bags king-sorted so each
// XCD (bid%8) walks a contiguous king range -> slice (393 KB) L2-resident.
// Per-bag preamble is ONE int4 broadcast load (meta), then the value loop.
// NOTE: accumulation order is FROZEN bit-exact (absmax margin 2.4%).
template <bool WAITER>
__device__ __forceinline__ void gather_body(
    const uint2* __restrict__ merged, const int* __restrict__ values,
    const int4* __restrict__ meta, float* __restrict__ out, int n_bags,
    int chunk, int b) {
  const int c = b & 7;          // XCD id under bid%8 round-robin
  const int j = b >> 3;         // sequence within this XCD's chunk
  const int pos = c * chunk + (j << 2) + (threadIdx.x >> 6);
  const int lim = min((c + 1) * chunk, n_bags);
  if (pos >= lim) return;
  const int lane = threadIdx.x & 63;
  const int4 md = meta[pos];
  const int len = md.y;
  const int base = md.z;
  const int* __restrict__ vals = values + md.x;
  const uint2* __restrict__ mb = merged + lane;  // lane covers dims 4l..4l+3

  float4 a0 = {0.f, 0.f, 0.f, 0.f}, a1 = {0.f, 0.f, 0.f, 0.f};

  int i = 0;
  for (; i + 8 <= len; i += 8) {
    const int v0 = vals[i],     v1 = vals[i + 1], v2 = vals[i + 2], v3 = vals[i + 3];
    const int v4 = vals[i + 4], v5 = vals[i + 5], v6 = vals[i + 6], v7 = vals[i + 7];
    unsigned r0, r1, r2, r3, r4, r5, r6, r7;
    if (WAITER) {
      const int k0 = v0 >> 6, k1 = v1 >> 6, k2 = v2 >> 6, k3 = v3 >> 6;
      const int k4 = v4 >> 6, k5 = v5 >> 6, k6 = v6 >> 6, k7 = v7 >> 6;
      r0 = base + ((k0 < 6 ? k0 + 6 : k0 - 6) << 6) + ((v0 & 63) ^ 56);
      r1 = base + ((k1 < 6 ? k1 + 6 : k1 - 6) << 6) + ((v1 & 63) ^ 56);
      r2 = base + ((k2 < 6 ? k2 + 6 : k2 - 6) << 6) + ((v2 & 63) ^ 56);
      r3 = base + ((k3 < 6 ? k3 + 6 : k3 - 6) << 6) + ((v3 & 63) ^ 56);
      r4 = base + ((k4 < 6 ? k4 + 6 : k4 - 6) << 6) + ((v4 & 63) ^ 56);
      r5 = base + ((k5 < 6 ? k5 + 6 : k5 - 6) << 6) + ((v5 & 63) ^ 56);
      r6 = base + ((k6 < 6 ? k6 + 6 : k6 - 6) << 6) + ((v6 & 63) ^ 56);
      r7 = base + ((k7 < 6 ? k7 + 6 : k7 - 6) << 6) + ((v7 & 63) ^ 56);
    } else {
      r0 = base + v0; r1 = base + v1; r2 = base + v2; r3 = base + v3;
      r4 = base + v4; r5 = base + v5; r6 = base + v6; r7 = base + v7;
    }
    const uint2 x0 = mb[(size_t)r0 << 6];
    const uint2 x1 = mb[(size_t)r1 << 6];
    const uint2 x2 = mb[(size_t)r2 << 6];
    const uint2 x3 = mb[(size_t)r3 << 6];
    const uint2 x4 = mb[(size_t)r4 << 6];
    const uint2 x5 = mb[(size_t)r5 << 6];
    const uint2 x6 = mb[(size_t)r6 << 6];
    const uint2 x7 = mb[(size_t)r7 << 6];
    bf4_acc(x0, a0); bf4_acc(x1, a1); bf4_acc(x2, a0); bf4_acc(x3, a1);
    bf4_acc(x4, a0); bf4_acc(x5, a1); bf4_acc(x6, a0); bf4_acc(x7, a1);
  }
  for (; i + 4 <= len; i += 4) {
    const int v0 = vals[i], v1 = vals[i + 1], v2 = vals[i + 2], v3 = vals[i + 3];
    unsigned r0, r1, r2, r3;
    if (WAITER) {
      const int k0 = v0 >> 6, k1 = v1 >> 6, k2 = v2 >> 6, k3 = v3 >> 6;
      r0 = base + ((k0 < 6 ? k0 + 6 : k0 - 6) << 6) + ((v0 & 63) ^ 56);
      r1 = base + ((k1 < 6 ? k1 + 6 : k1 - 6) << 6) + ((v1 & 63) ^ 56);
      r2 = base + ((k2 < 6 ? k2 + 6 : k2 - 6) << 6) + ((v2 & 63) ^ 56);
      r3 = base + ((k3 < 6 ? k3 + 6 : k3 - 6) << 6) + ((v3 & 63) ^ 56);
    } else {
      r0 = base + v0; r1 = base + v1; r2 = base + v2; r3 = base + v3;
    }
    const uint2 x0 = mb[(size_t)r0 << 6];
    const uint2 x1 = mb[(size_t)r1 << 6];
    const uint2 x2 = mb[(size_t)r2 << 6];
    const uint2 x3 = mb[(size_t)r3 << 6];
    bf4_acc(x0, a0); bf4_acc(x1, a1); bf4_acc(x2, a0); bf4_acc(x3, a1);
  }
  for (; i < len; ++i) {
    const int v = vals[i];
    unsigned r;
    if (WAITER) {
      const int k = v >> 6;
      r = base + ((k < 6 ? k + 6 : k - 6) << 6) + ((v & 63) ^ 56);
    } else {
      r = base + v;
    }
    bf4_acc(mb[(size_t)r << 6], a0);
  }

  float4 o;
  o.x = fminf(fmaxf(a0.x + a1.x, 0.f), 1.f);
  o.y = fminf(fmaxf(a0.y + a1.y, 0.f), 1.f);
  o.z = fminf(fmaxf(a0.z + a1.z, 0.f), 1.f);
  o.w = fminf(fmaxf(a0.w + a1.w, 0.f), 1.f);
  float4* ob = reinterpret_cast<float4*>(out) +
               (WAITER ? (size_t)n_bags * 64 : 0);
  ob[(size_t)md.w * 64 + lane] = o;
}

__global__ __launch_bounds__(256) void gather_kernel(
    const uint2* __restrict__ merged, const int* __restrict__ values,
    const int4* __restrict__ meta_m, const int4* __restrict__ meta_w,
    float* __restrict__ out, int n_bags, int chunk, int half_blocks) {
  const int b = blockIdx.x;
  if (b < half_blocks) {
    gather_body<false>(merged, values, meta_m, out, n_bags, chunk, b);
  } else {
    gather_body<true>(merged, values, meta_w, out, n_bags, chunk,
                      b - half_blocks);
  }
}

extern "C" void kernel_launch(void* const* d_in, const int* in_sizes, int n_in,
                              void* d_out, int out_size, void* d_ws, size_t ws_size,
                              hipStream_t stream) {
  const float* pieces = (const float*)d_in[0];
  const float* ranks  = (const float*)d_in[1];
  const float* files  = (const float*)d_in[2];
  const float* tiles  = (const float*)d_in[3];
  const float* mask   = (const float*)d_in[4];
  const int*   values = (const int*)d_in[5];
  const int*   lengths= (const int*)d_in[6];
  const int*   kings  = (const int*)d_in[7];
  float* out = (float*)d_out;

  const int B = in_sizes[6];  // number of bags

  // workspace layout (256B aligned): meta_m, meta_w (int4 each), merged table
  const size_t bM = ((size_t)B * 16 + 255) & ~(size_t)255;
  int4* meta_m = (int4*)d_ws;
  int4* meta_w = (int4*)((char*)d_ws + bM);
  uint2* merged = (uint2*)((char*)d_ws + 2 * bM);  // bf16 table, 25.2 MB

  prep_kernel<<<MATB + 1, 1024, 0, stream>>>(
      tiles, pieces, ranks, files, mask, merged, lengths, kings,
      meta_m, meta_w, B);

  const int chunk = (B + 7) / 8;                 // bags per XCD chunk
  const int half_blocks = 8 * ((chunk + 3) / 4); // blocks per view
  gather_kernel<<<2 * half_blocks, 256, 0, stream>>>(
      merged, values, meta_m, meta_w, out, B, chunk, half_blocks);
}

// Round 13
// 178.074 us; speedup vs baseline: 1.0423x; 1.0423x over previous
//
#include <hip/hip_runtime.h>

#define DOUT 256
#define NROWS 49152              // 64 king squares * 12 planes * 64 squares
#define NSEG (NROWS * 64)        // uint2 store segments (4 dims each)
#define MAT_THREADS (512 * 1024) // 512 blocks x 1024 threads, fully resident
#define SEG_PER_THREAD 6         // NSEG / MAT_THREADS

__device__ __forceinline__ float4 ld4(const float* p) {
  return *reinterpret_cast<const float4*>(p);
}

// round-to-nearest-even f32 -> bf16, packed pair (a in low16, b in high16)
__device__ __forceinline__ unsigned rne2(float a, float b) {
  unsigned ua = __float_as_uint(a), ub = __float_as_uint(b);
  ua += 0x7FFFu + ((ua >> 16) & 1u);
  ub += 0x7FFFu + ((ub >> 16) & 1u);
  return (ua >> 16) | (ub & 0xFFFF0000u);
}

// accumulate 4 bf16 (packed in uint2) into float4
__device__ __forceinline__ void bf4_acc(uint2 w, float4& acc) {
  acc.x += __uint_as_float(w.x << 16);
  acc.y += __uint_as_float(w.x & 0xFFFF0000u);
  acc.z += __uint_as_float(w.y << 16);
  acc.w += __uint_as_float(w.y & 0xFFFF0000u);
}

// prep: block 0 = index work -> king-sorted per-bag metadata
//   meta_m/meta_w[pos] = {ragged_off, len, rowBase(king), bag}
// blocks 1..512 = grid-stride bf16 table materialize (6 segments/thread,
// fully resident: 2 blocks/CU on all 256 CUs, no block churn).
__global__ __launch_bounds__(1024) void prep_kernel(
    const float* __restrict__ tiles, const float* __restrict__ pieces,
    const float* __restrict__ ranks, const float* __restrict__ files,
    const float* __restrict__ mask, uint2* __restrict__ merged,
    const int* __restrict__ lengths, const int* __restrict__ kings,
    int4* __restrict__ meta_m, int4* __restrict__ meta_w, int n_bags) {
  const int bid = blockIdx.x;
  const int t = threadIdx.x;
  if (bid == 0) {
    __shared__ int wsum[16];
    __shared__ int histM[16][64];
    __shared__ int histW[16][64];
    const int nb = n_bags;
    const int lane = t & 63;
    const int wid = t >> 6;
    // ---- zero hists (2048 ints / 1024 threads) ----
    ((int*)histM)[t] = 0;
    ((int*)histW)[t] = 0;
    // ---- lengths for this thread's 16 bags + local sum ----
    int v[16];
    const int base16 = t * 16;
    int s = 0;
    if (base16 + 16 <= nb) {
#pragma unroll
      for (int j = 0; j < 16; j += 4) {
        const int4 x = *reinterpret_cast<const int4*>(lengths + base16 + j);
        v[j] = x.x; v[j + 1] = x.y; v[j + 2] = x.z; v[j + 3] = x.w;
      }
#pragma unroll
      for (int j = 0; j < 16; ++j) s += v[j];
    } else {
      for (int j = 0; j < 16; ++j) {
        const int idx = base16 + j;
        v[j] = (idx < nb) ? lengths[idx] : 0;
        s += v[j];
      }
    }
    // ---- wave-level inclusive scan via shuffles ----
    int inc = s;
#pragma unroll
    for (int d = 1; d < 64; d <<= 1) {
      const int y = __shfl_up(inc, d, 64);
      if (lane >= d) inc += y;
    }
    if (lane == 63) wsum[wid] = inc;
    __syncthreads();
    if (wid == 0) {
      int wv = (lane < 16) ? wsum[lane] : 0;
#pragma unroll
      for (int d = 1; d < 16; d <<= 1) {
        const int y = __shfl_up(wv, d, 64);
        if (lane >= d) wv += y;
      }
      if (lane < 16) wsum[lane] = wv;  // inclusive wave totals
    }
    __syncthreads();
    const int waveBase = wid ? wsum[wid - 1] : 0;
    const int run0 = waveBase + inc - s;  // exclusive ragged offset of bag base16
    // ---- per-wave dual histogram ----
    for (int j = 0; j < 16; ++j) {
      const int idx = base16 + j;
      if (idx < nb) {
        const int2 kk = *reinterpret_cast<const int2*>(kings + 2 * idx);
        atomicAdd(&histM[wid][kk.x], 1);
        atomicAdd(&histW[wid][kk.y], 1);
      }
    }
    __syncthreads();
    // ---- bucket starts + per-wave cursor bases (wave0: M, wave1: W) ----
    if (wid < 2) {
      int (*h)[64] = wid ? histW : histM;
      const int k = lane;
      int sum = 0;
#pragma unroll
      for (int w = 0; w < 16; ++w) sum += h[w][k];
      int incl = sum;
#pragma unroll
      for (int d = 1; d < 64; d <<= 1) {
        const int y = __shfl_up(incl, d, 64);
        if (k >= d) incl += y;
      }
      int run = incl - sum;  // global bucket start
#pragma unroll
      for (int w = 0; w < 16; ++w) { const int c = h[w][k]; h[w][k] = run; run += c; }
    }
    __syncthreads();
    // ---- scatter packed metadata for both views ----
    int off = run0;
    for (int j = 0; j < 16; ++j) {
      const int idx = base16 + j;
      if (idx < nb) {
        const int2 kk = *reinterpret_cast<const int2*>(kings + 2 * idx);  // L1-hot
        const int len = v[j];
        const int pm = atomicAdd(&histM[wid][kk.x], 1);
        meta_m[pm] = make_int4(off, len, kk.x * 768, idx);
        const int sw = ((7 - (kk.y >> 3)) << 3) + (kk.y & 7);  // flipped king sq
        const int pw = atomicAdd(&histW[wid][kk.y], 1);
        meta_w[pw] = make_int4(off, len, sw * 768, idx);
        off += len;
      }
    }
    return;
  }
  // ---- materialize: grid-stride, 6 independent segments per thread ----
  const int tg = ((bid - 1) << 10) + t;  // 0 .. MAT_THREADS-1
#pragma unroll
  for (int it = 0; it < SEG_PER_THREAD; ++it) {
    const int seg = tg + it * MAT_THREADS;  // < NSEG
    const int row = seg >> 6;
    const int lane = seg & 63;
    const int p = row & 63;
    const int sk = row >> 6;
    const int r = p >> 3, f = p & 7;
    const float m = mask[row];
    const int d0 = lane << 2;
    const float4 tl = ld4(tiles + (size_t)row * DOUT + d0);
    const float4 pc = ld4(pieces + (size_t)sk * DOUT + d0);
    const float4 rk = ld4(ranks + (size_t)(sk * 8 + r) * DOUT + d0);
    const float4 fl = ld4(files + (size_t)(sk * 8 + f) * DOUT + d0);
    float4 o;
    o.x = fmaf(pc.x + rk.x + fl.x, m, tl.x);
    o.y = fmaf(pc.y + rk.y + fl.y, m, tl.y);
    o.z = fmaf(pc.z + rk.z + fl.z, m, tl.z);
    o.w = fmaf(pc.w + rk.w + fl.w, m, tl.w);
    uint2 w;
    w.x = rne2(o.x, o.y);
    w.y = rne2(o.z, o.w);
    merged[seg] = w;
  }
}

// gather: one wave per bag over the bf16 table; bags king-sorted so each
// XCD (bid%8) walks a contiguous king range -> slice (393 KB) L2-resident.
// Per-bag preamble is ONE int4 broadcast load (meta), then the value loop.
// NOTE: accumulation order is FROZEN bit-exact (absmax margin 2.4%).
template <bool WAITER>
__device__ __forceinline__ void gather_body(
    const uint2* __restrict__ merged, const int* __restrict__ values,
    const int4* __restrict__ meta, float* __restrict__ out, int n_bags,
    int chunk, int b) {
  const int c = b & 7;          // XCD id under bid%8 round-robin
  const int j = b >> 3;         // sequence within this XCD's chunk
  const int pos = c * chunk + (j << 2) + (threadIdx.x >> 6);
  const int lim = min((c + 1) * chunk, n_bags);
  if (pos >= lim) return;
  const int lane = threadIdx.x & 63;
  const int4 md = meta[pos];
  const int len = md.y;
  const int base = md.z;
  const int* __restrict__ vals = values + md.x;
  const uint2* __restrict__ mb = merged + lane;  // lane covers dims 4l..4l+3

  float4 a0 = {0.f, 0.f, 0.f, 0.f}, a1 = {0.f, 0.f, 0.f, 0.f};

  int i = 0;
  for (; i + 8 <= len; i += 8) {
    const int v0 = vals[i],     v1 = vals[i + 1], v2 = vals[i + 2], v3 = vals[i + 3];
    const int v4 = vals[i + 4], v5 = vals[i + 5], v6 = vals[i + 6], v7 = vals[i + 7];
    unsigned r0, r1, r2, r3, r4, r5, r6, r7;
    if (WAITER) {
      const int k0 = v0 >> 6, k1 = v1 >> 6, k2 = v2 >> 6, k3 = v3 >> 6;
      const int k4 = v4 >> 6, k5 = v5 >> 6, k6 = v6 >> 6, k7 = v7 >> 6;
      r0 = base + ((k0 < 6 ? k0 + 6 : k0 - 6) << 6) + ((v0 & 63) ^ 56);
      r1 = base + ((k1 < 6 ? k1 + 6 : k1 - 6) << 6) + ((v1 & 63) ^ 56);
      r2 = base + ((k2 < 6 ? k2 + 6 : k2 - 6) << 6) + ((v2 & 63) ^ 56);
      r3 = base + ((k3 < 6 ? k3 + 6 : k3 - 6) << 6) + ((v3 & 63) ^ 56);
      r4 = base + ((k4 < 6 ? k4 + 6 : k4 - 6) << 6) + ((v4 & 63) ^ 56);
      r5 = base + ((k5 < 6 ? k5 + 6 : k5 - 6) << 6) + ((v5 & 63) ^ 56);
      r6 = base + ((k6 < 6 ? k6 + 6 : k6 - 6) << 6) + ((v6 & 63) ^ 56);
      r7 = base + ((k7 < 6 ? k7 + 6 : k7 - 6) << 6) + ((v7 & 63) ^ 56);
    } else {
      r0 = base + v0; r1 = base + v1; r2 = base + v2; r3 = base + v3;
      r4 = base + v4; r5 = base + v5; r6 = base + v6; r7 = base + v7;
    }
    const uint2 x0 = mb[(size_t)r0 << 6];
    const uint2 x1 = mb[(size_t)r1 << 6];
    const uint2 x2 = mb[(size_t)r2 << 6];
    const uint2 x3 = mb[(size_t)r3 << 6];
    const uint2 x4 = mb[(size_t)r4 << 6];
    const uint2 x5 = mb[(size_t)r5 << 6];
    const uint2 x6 = mb[(size_t)r6 << 6];
    const uint2 x7 = mb[(size_t)r7 << 6];
    bf4_acc(x0, a0); bf4_acc(x1, a1); bf4_acc(x2, a0); bf4_acc(x3, a1);
    bf4_acc(x4, a0); bf4_acc(x5, a1); bf4_acc(x6, a0); bf4_acc(x7, a1);
  }
  for (; i + 4 <= len; i += 4) {
    const int v0 = vals[i], v1 = vals[i + 1], v2 = vals[i + 2], v3 = vals[i + 3];
    unsigned r0, r1, r2, r3;
    if (WAITER) {
      const int k0 = v0 >> 6, k1 = v1 >> 6, k2 = v2 >> 6, k3 = v3 >> 6;
      r0 = base + ((k0 < 6 ? k0 + 6 : k0 - 6) << 6) + ((v0 & 63) ^ 56);
      r1 = base + ((k1 < 6 ? k1 + 6 : k1 - 6) << 6) + ((v1 & 63) ^ 56);
      r2 = base + ((k2 < 6 ? k2 + 6 : k2 - 6) << 6) + ((v2 & 63) ^ 56);
      r3 = base + ((k3 < 6 ? k3 + 6 : k3 - 6) << 6) + ((v3 & 63) ^ 56);
    } else {
      r0 = base + v0; r1 = base + v1; r2 = base + v2; r3 = base + v3;
    }
    const uint2 x0 = mb[(size_t)r0 << 6];
    const uint2 x1 = mb[(size_t)r1 << 6];
    const uint2 x2 = mb[(size_t)r2 << 6];
    const uint2 x3 = mb[(size_t)r3 << 6];
    bf4_acc(x0, a0); bf4_acc(x1, a1); bf4_acc(x2, a0); bf4_acc(x3, a1);
  }
  for (; i < len; ++i) {
    const int v = vals[i];
    unsigned r;
    if (WAITER) {
      const int k = v >> 6;
      r = base + ((k < 6 ? k + 6 : k - 6) << 6) + ((v & 63) ^ 56);
    } else {
      r = base + v;
    }
    bf4_acc(mb[(size_t)r << 6], a0);
  }

  float4 o;
  o.x = fminf(fmaxf(a0.x + a1.x, 0.f), 1.f);
  o.y = fminf(fmaxf(a0.y + a1.y, 0.f), 1.f);
  o.z = fminf(fmaxf(a0.z + a1.z, 0.f), 1.f);
  o.w = fminf(fmaxf(a0.w + a1.w, 0.f), 1.f);
  float4* ob = reinterpret_cast<float4*>(out) +
               (WAITER ? (size_t)n_bags * 64 : 0);
  ob[(size_t)md.w * 64 + lane] = o;
}

__global__ __launch_bounds__(256) void gather_kernel(
    const uint2* __restrict__ merged, const int* __restrict__ values,
    const int4* __restrict__ meta_m, const int4* __restrict__ meta_w,
    float* __restrict__ out, int n_bags, int chunk, int half_blocks) {
  const int b = blockIdx.x;
  if (b < half_blocks) {
    gather_body<false>(merged, values, meta_m, out, n_bags, chunk, b);
  } else {
    gather_body<true>(merged, values, meta_w, out, n_bags, chunk,
                      b - half_blocks);
  }
}

extern "C" void kernel_launch(void* const* d_in, const int* in_sizes, int n_in,
                              void* d_out, int out_size, void* d_ws, size_t ws_size,
                              hipStream_t stream) {
  const float* pieces = (const float*)d_in[0];
  const float* ranks  = (const float*)d_in[1];
  const float* files  = (const float*)d_in[2];
  const float* tiles  = (const float*)d_in[3];
  const float* mask   = (const float*)d_in[4];
  const int*   values = (const int*)d_in[5];
  const int*   lengths= (const int*)d_in[6];
  const int*   kings  = (const int*)d_in[7];
  float* out = (float*)d_out;

  const int B = in_sizes[6];  // number of bags

  // workspace layout (256B aligned): meta_m, meta_w (int4 each), merged table
  const size_t bM = ((size_t)B * 16 + 255) & ~(size_t)255;
  int4* meta_m = (int4*)d_ws;
  int4* meta_w = (int4*)((char*)d_ws + bM);
  uint2* merged = (uint2*)((char*)d_ws + 2 * bM);  // bf16 table, 25.2 MB

  prep_kernel<<<513, 1024, 0, stream>>>(
      tiles, pieces, ranks, files, mask, merged, lengths, kings,
      meta_m, meta_w, B);

  const int chunk = (B + 7) / 8;                 // bags per XCD chunk
  const int half_blocks = 8 * ((chunk + 3) / 4); // blocks per view
  gather_kernel<<<2 * half_blocks, 256, 0, stream>>>(
      merged, values, meta_m, meta_w, out, B, chunk, half_blocks);
}